// Round 1
// baseline (516.441 us; speedup 1.0000x reference)
//
#include <hip/hip_runtime.h>
#include <math.h>

// Problem constants (fixed by the reference):
#define GP 8
#define GB 256
#define GN 512
#define GK 64

__device__ __forceinline__ void fma4(float4& acc, const float4 a, const float4 b) {
    acc.x += a.x * b.x; acc.y += a.y * b.y; acc.z += a.z * b.z; acc.w += a.w * b.w;
}
__device__ __forceinline__ float hsum4(const float4 a) {
    return (a.x + a.y) + (a.z + a.w);
}
__device__ __forceinline__ float reduce64(float s) {
    s += __shfl_xor(s, 1);  s += __shfl_xor(s, 2);  s += __shfl_xor(s, 4);
    s += __shfl_xor(s, 8);  s += __shfl_xor(s, 16); s += __shfl_xor(s, 32);
    return s;
}
__device__ __forceinline__ float reduce16(float s) {
    s += __shfl_xor(s, 1); s += __shfl_xor(s, 2);
    s += __shfl_xor(s, 4); s += __shfl_xor(s, 8);
    return s;
}

// One block per (p, b).
// Phase 1: one wave per WR row -> every wave-load is one contiguous 1 KB segment;
//          v fragments register-resident; explicit 8-deep float4 load batches for MLP.
// Phase 2: 4 consecutive WL rows per wave-load (contiguous 1 KB); WRx fragment hoisted.
__global__ __launch_bounds__(256, 4) void ghu_fused(
    const float* __restrict__ WL,
    const float* __restrict__ WR,
    const float* __restrict__ v_tm1,
    const float* __restrict__ v_t,
    const int*   __restrict__ ac_idx,
    const int*   __restrict__ pc_mask,
    float* __restrict__ out,       // [GB*GN v_next][GP*GB*GN dWL][GP*GB*GN dWR]
    float g, float inv_n)
{
    const int b    = blockIdx.x;
    const int p    = blockIdx.y;
    const int tid  = threadIdx.x;
    const int wave = tid >> 6;
    const int lane = tid & 63;

    __shared__ float s_vt[GN];     // for phase-2 g*v_t term (covered by phase-1 barrier)
    __shared__ float s_WRx[GK];
    __shared__ float s_Wx[GK];
    __shared__ float s_dWL[GN];
    __shared__ float s_vnext[GN];

    const bool  sel   = (ac_idx[b] == p);          // block-uniform
    const float maskv = (float)pc_mask[b * GP + p];

    const float4* v4u = (const float4*)(v_tm1 + b * GN);   // 128 float4
    const float4* v4t = (const float4*)(v_t   + b * GN);

    // Stage v_t for phase 2 (consumed only after the phase-1 barrier).
    if (tid < 128) ((float4*)s_vt)[tid] = v4t[tid];

    // ---- Phase 1: WRx[k] = WR[p,b,k,:]·v_tm1 (and ·v_t when selected) ----
    {
        // Per-lane v fragments, register-resident for the whole phase.
        const float4 vu_lo = v4u[lane];
        const float4 vu_hi = v4u[64 + lane];
        float4 vt_lo, vt_hi;
        if (sel) { vt_lo = v4t[lane]; vt_hi = v4t[64 + lane]; }

        const float4* WR4 = (const float4*)(WR + (size_t)(p * GB + b) * (GK * GN));
        const int k0 = wave * 16;      // 16 rows per wave

        for (int rr = 0; rr < 16; rr += 4) {
            float4 a[8];               // 8 contiguous 1 KB wave-loads in flight
            #pragma unroll
            for (int j = 0; j < 4; ++j) {
                const int k = k0 + rr + j;
                a[2 * j]     = WR4[k * 128 + lane];        // row k, first half
                a[2 * j + 1] = WR4[k * 128 + 64 + lane];   // row k, second half
            }
            #pragma unroll
            for (int j = 0; j < 4; ++j) {
                const int k = k0 + rr + j;
                float4 acc = make_float4(0.f, 0.f, 0.f, 0.f);
                fma4(acc, a[2 * j],     vu_lo);
                fma4(acc, a[2 * j + 1], vu_hi);
                const float s = reduce64(hsum4(acc));
                if (lane == 0) s_WRx[k] = s;
                if (sel) {
                    float4 acc2 = make_float4(0.f, 0.f, 0.f, 0.f);
                    fma4(acc2, a[2 * j],     vt_lo);
                    fma4(acc2, a[2 * j + 1], vt_hi);
                    const float s2 = reduce64(hsum4(acc2));
                    if (lane == 0) s_Wx[k] = s2;
                }
            }
        }
    }
    __syncthreads();

    // ---- Phase 2: dWL-core[n] = WL[p,b,n,:]·WRx (+ v_next when selected) ----
    {
        const float4 wrx = ((const float4*)s_WRx)[lane & 15];  // k = 4*(lane&15)..+3
        float4 wx;
        if (sel) wx = ((const float4*)s_Wx)[lane & 15];

        const float4* WL4 = (const float4*)(WL + (size_t)(p * GB + b) * (GN * GK));
        const int sub = lane >> 4;     // row-within-load, 0..3

        for (int it = 0; it < 4; ++it) {
            const int n0 = wave * 128 + it * 32;   // 32 rows per batch
            float4 a[8];               // 8 contiguous 1 KB wave-loads in flight
            #pragma unroll
            for (int j = 0; j < 8; ++j) {
                a[j] = WL4[(n0 + 4 * j) * 16 + lane];   // rows n0+4j .. n0+4j+3
            }
            #pragma unroll
            for (int j = 0; j < 8; ++j) {
                const int n = n0 + 4 * j + sub;
                float4 acc = make_float4(0.f, 0.f, 0.f, 0.f);
                fma4(acc, a[j], wrx);
                const float d = reduce16(hsum4(acc));
                if ((lane & 15) == 0) s_dWL[n] = (g * s_vt[n] - d) * maskv;
                if (sel) {
                    float4 acc2 = make_float4(0.f, 0.f, 0.f, 0.f);
                    fma4(acc2, a[j], wx);
                    const float d2 = reduce16(hsum4(acc2));
                    if ((lane & 15) == 0) s_vnext[n] = tanhf(d2);
                }
            }
        }
    }
    __syncthreads();

    // ---- Epilogue: coalesced contiguous writes ----
    const size_t pbN = (size_t)(p * GB + b) * GN;
    float* dWL_out = out + (size_t)GB * GN + pbN;
    float* dWR_out = out + (size_t)GB * GN + (size_t)GP * GB * GN + pbN;

    dWL_out[tid]       = s_dWL[tid];
    dWL_out[tid + 256] = s_dWL[tid + 256];

    const float sc = maskv * inv_n;
    dWR_out[tid]       = v_tm1[b * GN + tid] * sc;
    dWR_out[tid + 256] = v_tm1[b * GN + tid + 256] * sc;

    if (sel) {
        out[b * GN + tid]       = s_vnext[tid];
        out[b * GN + tid + 256] = s_vnext[tid + 256];
    }
}

extern "C" void kernel_launch(void* const* d_in, const int* in_sizes, int n_in,
                              void* d_out, int out_size, void* d_ws, size_t ws_size,
                              hipStream_t stream) {
    const float* WL     = (const float*)d_in[0];
    const float* WR     = (const float*)d_in[1];
    const float* v_tm1  = (const float*)d_in[2];
    const float* v_t    = (const float*)d_in[3];
    const int*   ac_idx = (const int*)d_in[4];
    const int*   pc_msk = (const int*)d_in[5];
    float* out = (float*)d_out;

    const double RHO = 0.999;
    const float g     = (float)(0.5 * (log(1.0 + RHO) - log(1.0 - RHO)) / RHO);
    const float inv_n = (float)(1.0 / ((double)GN * RHO * RHO));

    dim3 grid(GB, GP);
    ghu_fused<<<grid, 256, 0, stream>>>(WL, WR, v_tm1, v_t, ac_idx, pc_msk,
                                        out, g, inv_n);
}